// Round 2
// baseline (505.761 us; speedup 1.0000x reference)
//
#include <hip/hip_runtime.h>
#include <stdint.h>

// Problem constants (from reference) — all inputs/outputs are FP32.
#define T_DIM 16
#define M_DIM 1024
#define N_NODES 10000
#define NB 100
#define KI 4096             // i dimension (4*M)
#define KP 8192             // interleaved i' = 2*i + o (memory-contiguous axis of weight)
#define CHUNKS 4
#define I_CHUNK (KI / CHUNKS)        // 1024 i-values per chunk
#define STEPS ((KP / CHUNKS) / 32)   // 64 MFMA k-steps per chunk
#define PITCH (I_CHUNK + 4)          // bf16 LDS row pitch: 1028 shorts (8B aligned; 514 words %32=2 -> conflict-free)
#define TILES 625                    // 10000 / 16

typedef short short8 __attribute__((ext_vector_type(8)));
typedef float f32x4 __attribute__((ext_vector_type(4)));

__device__ __forceinline__ unsigned int fbits(float f) {
    return __builtin_bit_cast(unsigned int, f);
}
// fp32 -> bf16 (RNE), returns in low 16 bits
__device__ __forceinline__ unsigned int bf16rne(unsigned int u) {
    return (u + 0x7FFFu + ((u >> 16) & 1u)) >> 16;
}
__device__ __forceinline__ unsigned int pack2bf(float a, float b) {
    return bf16rne(fbits(a)) | (bf16rne(fbits(b)) << 16);
}

// ---------------------------------------------------------------------------
// GEMM: f[n,t,o] = sum_i x_out[t,i] * W[n,i,o]   (fp32 in, fp32 acc, bf16 MFMA)
// K' = 8192 interleaved (i,o). B fragment = 8 consecutive fp32 weights/lane,
// converted to bf16 in-register. A0/A1 = x_out with zeros at odd/even k'
// slots -> o=0 / o=1 accumulators (two MFMAs share one weight load).
// grid = (157 tile-groups, 4 K-chunks) x 256 threads (4 waves, 1 tile each).
// ---------------------------------------------------------------------------
__global__ __launch_bounds__(256) void gemm_kernel(
    const float* __restrict__ x,       // fp32 [16][3][1024]
    const float* __restrict__ weight,  // fp32 [10000][4096][2]
    float* __restrict__ fws)           // fp32 [10000][16][2], pre-zeroed
{
    __shared__ unsigned short lds_x[T_DIM * PITCH];   // x_out chunk as bf16

    const int tid = threadIdx.x;
    const int chunk = blockIdx.y;

    // Stage this chunk's x_out[t, i] into LDS as bf16.
    // x_out[t, 4m + {0,1,2,3}] = [x[t,0,m], x[t,2,m], x[t,2,m], x[t,1,m]]
    for (int q = tid; q < T_DIM * (I_CHUNK / 4); q += 256) {
        int t = q >> 8;            // I_CHUNK/4 == 256 per t
        int mloc = q & 255;
        int m = chunk * 256 + mloc;
        const float* xb = x + t * 3 * M_DIM + m;
        float v0 = xb[0];
        float v1 = xb[M_DIM];
        float v2 = xb[2 * M_DIM];
        unsigned int w0 = pack2bf(v0, v2);   // slots 4m+0, 4m+1
        unsigned int w1 = pack2bf(v2, v1);   // slots 4m+2, 4m+3
        *(uint2*)&lds_x[t * PITCH + mloc * 4] = make_uint2(w0, w1);
    }
    __syncthreads();

    const int wave = tid >> 6;
    const int lane = tid & 63;
    const int tile = blockIdx.x * 4 + wave;
    if (tile >= TILES) return;   // after the only barrier

    const int col = lane & 15;   // n within tile (B/C col)
    const int quad = lane >> 4;  // k-group
    const int n = tile * 16 + col;

    // B source: lane holds W'[k' = quad*8 + j][n], j contiguous in memory (fp32).
    const float* wp =
        weight + (size_t)n * KP + (size_t)chunk * (KP / CHUNKS) + quad * 8;
    // A source: 4 consecutive bf16 x_out values for t = lane&15.
    const unsigned short* xrow = &lds_x[(lane & 15) * PITCH + quad * 4];

    f32x4 acc0 = {0.f, 0.f, 0.f, 0.f};
    f32x4 acc1 = {0.f, 0.f, 0.f, 0.f};

    float4 flo = *(const float4*)wp;
    float4 fhi = *(const float4*)(wp + 4);
    for (int s = 0; s < STEPS; ++s) {
        float4 lo = flo, hi = fhi;
        if (s + 1 < STEPS) {
            flo = *(const float4*)(wp + (s + 1) * 32);
            fhi = *(const float4*)(wp + (s + 1) * 32 + 4);
        }

        // Pack 8 fp32 weights -> 8 bf16 B fragment (k'-order = memory order).
        union { unsigned int ui[4]; short8 v; } B;
        B.ui[0] = pack2bf(lo.x, lo.y);
        B.ui[1] = pack2bf(lo.z, lo.w);
        B.ui[2] = pack2bf(hi.x, hi.y);
        B.ui[3] = pack2bf(hi.z, hi.w);

        uint2 u = *(const uint2*)(xrow + s * 16);
        union { unsigned int ui[4]; short8 v; } A0, A1;
        // A0: x values at even k'-slots (o=0 weights), A1: odd k'-slots (o=1).
        A0.ui[0] = u.x & 0xFFFFu;      A0.ui[1] = u.x >> 16;
        A0.ui[2] = u.y & 0xFFFFu;      A0.ui[3] = u.y >> 16;
        A1.ui[0] = u.x << 16;          A1.ui[1] = u.x & 0xFFFF0000u;
        A1.ui[2] = u.y << 16;          A1.ui[3] = u.y & 0xFFFF0000u;

        acc0 = __builtin_amdgcn_mfma_f32_16x16x32_bf16(A0.v, B.v, acc0, 0, 0, 0);
        acc1 = __builtin_amdgcn_mfma_f32_16x16x32_bf16(A1.v, B.v, acc1, 0, 0, 0);
    }

    // C/D layout: col = lane&15, row(t) = quad*4 + reg. Combine K-chunks via atomics.
    #pragma unroll
    for (int r = 0; r < 4; ++r) {
        int t = quad * 4 + r;
        atomicAdd(&fws[((size_t)n * T_DIM + t) * 2 + 0], acc0[r]);
        atomicAdd(&fws[((size_t)n * T_DIM + t) * 2 + 1], acc1[r]);
    }
}

// ---------------------------------------------------------------------------
// Gather f_in = f[node_in-1] (256000 fp32) + boundary sums f_b (96 fp32).
// ---------------------------------------------------------------------------
__global__ __launch_bounds__(256) void gather_kernel(
    const float* __restrict__ fws,
    const int* __restrict__ node_in,
    const int* __restrict__ top, const int* __restrict__ bottom,
    const int* __restrict__ left, const int* __restrict__ right,
    float* __restrict__ out)
{
    const int tid = threadIdx.x;
    if (blockIdx.x < 1000) {
        int e = blockIdx.x * 256 + tid;        // < 256000
        int j = e >> 5;                        // node_in index
        int rem = e & 31;                      // t*2 + o
        int node = node_in[j] - 1;
        out[e] = fws[(size_t)node * 32 + rem];
    } else {
        __shared__ float red[256];
        __shared__ float sums[64];
        const int l = tid >> 6;                // 0=top 1=bottom 2=left 3=right
        const int t = (tid >> 2) & 15;
        const int p = tid & 3;
        const int* lists[4] = {top, bottom, left, right};
        const int osel = (l < 2) ? 1 : 0;
        const int* lp = lists[l];
        float s = 0.f;
        for (int idx = p; idx < NB; idx += 4)
            s += fws[(size_t)(lp[idx] - 1) * 32 + t * 2 + osel];
        red[tid] = s;
        __syncthreads();
        if (p == 0)
            sums[tid >> 2] = red[tid] + red[tid + 1] + red[tid + 2] + red[tid + 3];
        __syncthreads();
        if (tid < 96) {
            int row = tid >> 4;                // 0..5 -> [top,bot,left,right,t+b,l+r]
            int tt = tid & 15;
            float v;
            if (row < 4)       v = sums[row * 16 + tt];
            else if (row == 4) v = sums[0 * 16 + tt] + sums[1 * 16 + tt];
            else               v = sums[2 * 16 + tt] + sums[3 * 16 + tt];
            out[256000 + tid] = v;
        }
    }
}

extern "C" void kernel_launch(void* const* d_in, const int* in_sizes, int n_in,
                              void* d_out, int out_size, void* d_ws, size_t ws_size,
                              hipStream_t stream)
{
    const float* x      = (const float*)d_in[0];
    const float* weight = (const float*)d_in[1];
    const int* node_in = (const int*)d_in[2];
    const int* top     = (const int*)d_in[3];
    const int* bottom  = (const int*)d_in[4];
    const int* left    = (const int*)d_in[5];
    const int* right   = (const int*)d_in[6];
    float* fws = (float*)d_ws;                 // 10000*32 fp32 = 1.28 MB
    float* out = (float*)d_out;                // fp32: 256000 f_in + 96 f_b

    hipMemsetAsync(fws, 0, (size_t)N_NODES * 2 * T_DIM * sizeof(float), stream);

    dim3 grid((TILES + 3) / 4, CHUNKS);        // 157 x 4
    gemm_kernel<<<grid, 256, 0, stream>>>(x, weight, fws);
    gather_kernel<<<1001, 256, 0, stream>>>(fws, node_in, top, bottom, left, right, out);
}

// Round 3
// 500.887 us; speedup vs baseline: 1.0097x; 1.0097x over previous
//
#include <hip/hip_runtime.h>
#include <stdint.h>

// Problem constants (from reference) — all inputs/outputs are FP32.
#define T_DIM 16
#define M_DIM 1024
#define N_NODES 10000
#define NB 100
#define KI 4096             // i dimension (4*M)
#define KP 8192             // interleaved i' = 2*i + o (memory-contiguous axis of weight)
#define CHUNKS 8
#define I_CHUNK (KI / CHUNKS)        // 512 i-values per chunk
#define M_CHUNK (I_CHUNK / 4)        // 128 m-values per chunk
#define STEPS ((KP / CHUNKS) / 32)   // 32 MFMA k-steps per chunk
#define PITCH (I_CHUNK + 4)          // 516 shorts row pitch (8B aligned; 258 words %32=2 -> conflict-free)
#define TILES 625                    // 10000 / 16
#define SLAB (N_NODES * T_DIM * 2)   // 320000 floats per chunk-slab

typedef short short8 __attribute__((ext_vector_type(8)));
typedef float f32x4 __attribute__((ext_vector_type(4)));

__device__ __forceinline__ unsigned int fbits(float f) {
    return __builtin_bit_cast(unsigned int, f);
}
// fp32 -> bf16 (RNE), result in low 16 bits
__device__ __forceinline__ unsigned int bf16rne(unsigned int u) {
    return (u + 0x7FFFu + ((u >> 16) & 1u)) >> 16;
}
__device__ __forceinline__ unsigned int pack2bf(float a, float b) {
    return bf16rne(fbits(a)) | (bf16rne(fbits(b)) << 16);
}

// ---------------------------------------------------------------------------
// GEMM: f[n,t,o] = sum_i x_out[t,i] * W[n,i,o]   (fp32 in, fp32 acc, bf16 MFMA)
// K' = 8192 interleaved (i,o). B fragment = 8 consecutive fp32 weights/lane,
// converted to bf16 in-register. A0/A1 = x_out with zeros at odd/even k'
// slots -> o=0 / o=1 accumulators (two MFMAs share one weight load).
// Each wave owns one (16-n tile, K-chunk) pair and writes its partial sums
// to a per-chunk slab with plain stores — no atomics, no workspace zeroing.
// grid = (157 tile-groups, 8 K-chunks) x 256 threads (4 waves, 1 tile each).
// ---------------------------------------------------------------------------
__global__ __launch_bounds__(256) void gemm_kernel(
    const float* __restrict__ x,       // fp32 [16][3][1024]
    const float* __restrict__ weight,  // fp32 [10000][4096][2]
    float* __restrict__ fws)           // fp32 [8][10000][16][2] partial slabs
{
    __shared__ unsigned short lds_x[T_DIM * PITCH];   // x_out chunk as bf16

    const int tid = threadIdx.x;
    const int chunk = blockIdx.y;

    // Stage this chunk's x_out[t, i] into LDS as bf16.
    // x_out[t, 4m + {0,1,2,3}] = [x[t,0,m], x[t,2,m], x[t,2,m], x[t,1,m]]
    for (int q = tid; q < T_DIM * M_CHUNK; q += 256) {
        int t = q >> 7;            // M_CHUNK == 128 per t
        int mloc = q & 127;
        int m = chunk * M_CHUNK + mloc;
        const float* xb = x + t * 3 * M_DIM + m;
        float v0 = xb[0];
        float v1 = xb[M_DIM];
        float v2 = xb[2 * M_DIM];
        unsigned int w0 = pack2bf(v0, v2);   // slots 4m+0, 4m+1
        unsigned int w1 = pack2bf(v2, v1);   // slots 4m+2, 4m+3
        *(uint2*)&lds_x[t * PITCH + mloc * 4] = make_uint2(w0, w1);
    }
    __syncthreads();

    const int wave = tid >> 6;
    const int lane = tid & 63;
    const int tile = blockIdx.x * 4 + wave;
    if (tile >= TILES) return;   // after the only barrier

    const int col = lane & 15;   // n within tile (B/C col)
    const int quad = lane >> 4;  // k-group
    const int n = tile * 16 + col;

    // B source: lane holds W'[k' = quad*8 + j][n], j contiguous in memory (fp32).
    const float* wp =
        weight + (size_t)n * KP + (size_t)chunk * (KP / CHUNKS) + quad * 8;
    // A source: 4 consecutive bf16 x_out values for t = lane&15.
    const unsigned short* xrow = &lds_x[(lane & 15) * PITCH + quad * 4];

    f32x4 acc0 = {0.f, 0.f, 0.f, 0.f};
    f32x4 acc1 = {0.f, 0.f, 0.f, 0.f};

    float4 flo = *(const float4*)wp;
    float4 fhi = *(const float4*)(wp + 4);
    #pragma unroll 4
    for (int s = 0; s < STEPS; ++s) {
        float4 lo = flo, hi = fhi;
        if (s + 1 < STEPS) {
            flo = *(const float4*)(wp + (s + 1) * 32);
            fhi = *(const float4*)(wp + (s + 1) * 32 + 4);
        }

        // Pack 8 fp32 weights -> 8 bf16 B fragment (k'-order = memory order).
        union { unsigned int ui[4]; short8 v; } B;
        B.ui[0] = pack2bf(lo.x, lo.y);
        B.ui[1] = pack2bf(lo.z, lo.w);
        B.ui[2] = pack2bf(hi.x, hi.y);
        B.ui[3] = pack2bf(hi.z, hi.w);

        uint2 u = *(const uint2*)(xrow + s * 16);
        union { unsigned int ui[4]; short8 v; } A0, A1;
        // A0: x values at even k'-slots (o=0 weights), A1: odd k'-slots (o=1).
        A0.ui[0] = u.x & 0xFFFFu;      A0.ui[1] = u.x >> 16;
        A0.ui[2] = u.y & 0xFFFFu;      A0.ui[3] = u.y >> 16;
        A1.ui[0] = u.x << 16;          A1.ui[1] = u.x & 0xFFFF0000u;
        A1.ui[2] = u.y << 16;          A1.ui[3] = u.y & 0xFFFF0000u;

        acc0 = __builtin_amdgcn_mfma_f32_16x16x32_bf16(A0.v, B.v, acc0, 0, 0, 0);
        acc1 = __builtin_amdgcn_mfma_f32_16x16x32_bf16(A1.v, B.v, acc1, 0, 0, 0);
    }

    // C/D layout: col = lane&15, row(t) = quad*4 + reg.
    // Plain float2 stores into this chunk's slab (each addr written once).
    float* slab = fws + (size_t)chunk * SLAB;
    #pragma unroll
    for (int r = 0; r < 4; ++r) {
        int t = quad * 4 + r;
        *(float2*)&slab[((size_t)n * T_DIM + t) * 2] = make_float2(acc0[r], acc1[r]);
    }
}

// ---------------------------------------------------------------------------
// Gather f_in = f[node_in-1] (256000 fp32) + boundary sums f_b (96 fp32).
// f = sum of the 8 chunk slabs.
// ---------------------------------------------------------------------------
__global__ __launch_bounds__(256) void gather_kernel(
    const float* __restrict__ fws,
    const int* __restrict__ node_in,
    const int* __restrict__ top, const int* __restrict__ bottom,
    const int* __restrict__ left, const int* __restrict__ right,
    float* __restrict__ out)
{
    const int tid = threadIdx.x;
    if (blockIdx.x < 1000) {
        int e = blockIdx.x * 256 + tid;        // < 256000
        int j = e >> 5;                        // node_in index
        int rem = e & 31;                      // t*2 + o
        size_t base = (size_t)(node_in[j] - 1) * 32 + rem;
        float v = 0.f;
        #pragma unroll
        for (int c = 0; c < CHUNKS; ++c) v += fws[c * (size_t)SLAB + base];
        out[e] = v;
    } else {
        __shared__ float red[256];
        __shared__ float sums[64];
        const int l = tid >> 6;                // 0=top 1=bottom 2=left 3=right
        const int t = (tid >> 2) & 15;
        const int p = tid & 3;
        const int* lists[4] = {top, bottom, left, right};
        const int osel = (l < 2) ? 1 : 0;
        const int* lp = lists[l];
        float s = 0.f;
        for (int idx = p; idx < NB; idx += 4) {
            size_t base = (size_t)(lp[idx] - 1) * 32 + t * 2 + osel;
            #pragma unroll
            for (int c = 0; c < CHUNKS; ++c) s += fws[c * (size_t)SLAB + base];
        }
        red[tid] = s;
        __syncthreads();
        if (p == 0)
            sums[tid >> 2] = red[tid] + red[tid + 1] + red[tid + 2] + red[tid + 3];
        __syncthreads();
        if (tid < 96) {
            int row = tid >> 4;                // 0..5 -> [top,bot,left,right,t+b,l+r]
            int tt = tid & 15;
            float v;
            if (row < 4)       v = sums[row * 16 + tt];
            else if (row == 4) v = sums[0 * 16 + tt] + sums[1 * 16 + tt];
            else               v = sums[2 * 16 + tt] + sums[3 * 16 + tt];
            out[256000 + tid] = v;
        }
    }
}

extern "C" void kernel_launch(void* const* d_in, const int* in_sizes, int n_in,
                              void* d_out, int out_size, void* d_ws, size_t ws_size,
                              hipStream_t stream)
{
    const float* x      = (const float*)d_in[0];
    const float* weight = (const float*)d_in[1];
    const int* node_in = (const int*)d_in[2];
    const int* top     = (const int*)d_in[3];
    const int* bottom  = (const int*)d_in[4];
    const int* left    = (const int*)d_in[5];
    const int* right   = (const int*)d_in[6];
    float* fws = (float*)d_ws;                 // 8 slabs x 1.28 MB = 10.24 MB
    float* out = (float*)d_out;                // fp32: 256000 f_in + 96 f_b

    dim3 grid((TILES + 3) / 4, CHUNKS);        // 157 x 8
    gemm_kernel<<<grid, 256, 0, stream>>>(x, weight, fws);
    gather_kernel<<<1001, 256, 0, stream>>>(fws, node_in, top, bottom, left, right, out);
}

// Round 4
// 466.736 us; speedup vs baseline: 1.0836x; 1.0732x over previous
//
#include <hip/hip_runtime.h>
#include <stdint.h>

// Problem constants (from reference) — all inputs/outputs are FP32.
#define T_DIM 16
#define M_DIM 1024
#define N_NODES 10000
#define NB 100
#define N_IN 8000
#define KI 4096             // i dimension (4*M)
#define KP 8192             // interleaved i' = 2*i + o (memory-contiguous axis of weight)
#define CHUNKS 8
#define I_CHUNK (KI / CHUNKS)        // 512 i-values per chunk
#define M_CHUNK (I_CHUNK / 4)        // 128 m-values per chunk
#define STEPS ((KP / CHUNKS) / 32)   // 32 MFMA k-steps per chunk
#define PITCH (I_CHUNK + 4)          // 516 shorts row pitch (8B aligned; 258 words %32=2 -> conflict-free)
#define TILES 625                    // ceil over all 10000 nodes (worst case)
#define SLAB (N_NODES * T_DIM * 2)   // 320000 floats per chunk-slab

typedef short short8 __attribute__((ext_vector_type(8)));
typedef float f32x4 __attribute__((ext_vector_type(4)));

__device__ __forceinline__ unsigned int fbits(float f) {
    return __builtin_bit_cast(unsigned int, f);
}
// fp32 -> bf16 (RNE), result in low 16 bits
__device__ __forceinline__ unsigned int bf16rne(unsigned int u) {
    return (u + 0x7FFFu + ((u >> 16) & 1u)) >> 16;
}
__device__ __forceinline__ unsigned int pack2bf(float a, float b) {
    return bf16rne(fbits(a)) | (bf16rne(fbits(b)) << 16);
}

// ---------------------------------------------------------------------------
// Prep 1: flag every referenced node. Workspace poison is 0xAAAAAAAA, so
// "flag==1" is unambiguous without zeroing. Thread 0 also resets the counter.
// ---------------------------------------------------------------------------
__global__ __launch_bounds__(256) void flag_kernel(
    const int* __restrict__ node_in,
    const int* __restrict__ top, const int* __restrict__ bottom,
    const int* __restrict__ left, const int* __restrict__ right,
    int* __restrict__ flags, int* __restrict__ counter)
{
    int i = blockIdx.x * 256 + threadIdx.x;
    if (i == 0) *counter = 0;
    int v;
    if (i < N_IN)               v = node_in[i];
    else if (i < N_IN + NB)     v = top[i - N_IN];
    else if (i < N_IN + 2*NB)   v = bottom[i - N_IN - NB];
    else if (i < N_IN + 3*NB)   v = left[i - N_IN - 2*NB];
    else if (i < N_IN + 4*NB)   v = right[i - N_IN - 3*NB];
    else return;
    flags[v - 1] = 1;
}

// ---------------------------------------------------------------------------
// Prep 2: compact flagged node ids into a dense list (order irrelevant).
// atomicAdd(p,1) is wave-aggregated by the compiler -> ~157 real atomics.
// ---------------------------------------------------------------------------
__global__ __launch_bounds__(256) void compact_kernel(
    const int* __restrict__ flags, int* __restrict__ counter,
    int* __restrict__ list)
{
    int i = blockIdx.x * 256 + threadIdx.x;
    if (i < N_NODES && flags[i] == 1) {
        int pos = atomicAdd(counter, 1);
        list[pos] = i;
    }
}

// ---------------------------------------------------------------------------
// GEMM over REFERENCED nodes only: f[n,t,o] = sum_i x_out[t,i] * W[n,i,o]
// (fp32 in, fp32 acc, bf16 MFMA). K' = 8192 interleaved (i,o). B fragment =
// 8 consecutive fp32 weights/lane converted to bf16 in-register. A0/A1 =
// x_out with zeros at odd/even k' slots -> o=0 / o=1 accumulators (two MFMAs
// share one weight load). Each wave owns one (16-node tile from `list`,
// K-chunk) pair; partials go to per-chunk slabs with plain stores.
// Lanes past `count` recompute node 0 (same-value benign stores).
// grid = (157 tile-groups, 8 K-chunks) x 256 threads (4 waves, 1 tile each).
// ---------------------------------------------------------------------------
__global__ __launch_bounds__(256) void gemm_kernel(
    const float* __restrict__ x,       // fp32 [16][3][1024]
    const float* __restrict__ weight,  // fp32 [10000][4096][2]
    const int* __restrict__ list,      // compacted referenced node ids
    const int* __restrict__ counter,   // number of referenced nodes
    float* __restrict__ fws)           // fp32 [8][10000][16][2] partial slabs
{
    __shared__ unsigned short lds_x[T_DIM * PITCH];   // x_out chunk as bf16

    const int tid = threadIdx.x;
    const int chunk = blockIdx.y;

    // Stage this chunk's x_out[t, i] into LDS as bf16.
    // x_out[t, 4m + {0,1,2,3}] = [x[t,0,m], x[t,2,m], x[t,2,m], x[t,1,m]]
    for (int q = tid; q < T_DIM * M_CHUNK; q += 256) {
        int t = q >> 7;            // M_CHUNK == 128 per t
        int mloc = q & 127;
        int m = chunk * M_CHUNK + mloc;
        const float* xb = x + t * 3 * M_DIM + m;
        float v0 = xb[0];
        float v1 = xb[M_DIM];
        float v2 = xb[2 * M_DIM];
        unsigned int w0 = pack2bf(v0, v2);   // slots 4m+0, 4m+1
        unsigned int w1 = pack2bf(v2, v1);   // slots 4m+2, 4m+3
        *(uint2*)&lds_x[t * PITCH + mloc * 4] = make_uint2(w0, w1);
    }
    __syncthreads();

    const int cnt = *counter;                 // wave-uniform scalar
    const int wave = tid >> 6;
    const int lane = tid & 63;
    const int tile = blockIdx.x * 4 + wave;
    if (tile * 16 >= cnt) return;             // whole wave unneeded

    const int col = lane & 15;   // n-slot within tile (B/C col)
    const int quad = lane >> 4;  // k-group
    const int idx = tile * 16 + col;
    const int n = (idx < cnt) ? list[idx] : 0;

    // B source: lane holds W'[k' = quad*8 + j][n], j contiguous in memory (fp32).
    const float* wp =
        weight + (size_t)n * KP + (size_t)chunk * (KP / CHUNKS) + quad * 8;
    // A source: 4 consecutive bf16 x_out values for t = lane&15.
    const unsigned short* xrow = &lds_x[(lane & 15) * PITCH + quad * 4];

    f32x4 acc0 = {0.f, 0.f, 0.f, 0.f};
    f32x4 acc1 = {0.f, 0.f, 0.f, 0.f};

    float4 flo = *(const float4*)wp;
    float4 fhi = *(const float4*)(wp + 4);
    #pragma unroll 4
    for (int s = 0; s < STEPS; ++s) {
        float4 lo = flo, hi = fhi;
        if (s + 1 < STEPS) {
            flo = *(const float4*)(wp + (s + 1) * 32);
            fhi = *(const float4*)(wp + (s + 1) * 32 + 4);
        }

        // Pack 8 fp32 weights -> 8 bf16 B fragment (k'-order = memory order).
        union { unsigned int ui[4]; short8 v; } B;
        B.ui[0] = pack2bf(lo.x, lo.y);
        B.ui[1] = pack2bf(lo.z, lo.w);
        B.ui[2] = pack2bf(hi.x, hi.y);
        B.ui[3] = pack2bf(hi.z, hi.w);

        uint2 u = *(const uint2*)(xrow + s * 16);
        union { unsigned int ui[4]; short8 v; } A0, A1;
        // A0: x values at even k'-slots (o=0 weights), A1: odd k'-slots (o=1).
        A0.ui[0] = u.x & 0xFFFFu;      A0.ui[1] = u.x >> 16;
        A0.ui[2] = u.y & 0xFFFFu;      A0.ui[3] = u.y >> 16;
        A1.ui[0] = u.x << 16;          A1.ui[1] = u.x & 0xFFFF0000u;
        A1.ui[2] = u.y << 16;          A1.ui[3] = u.y & 0xFFFF0000u;

        acc0 = __builtin_amdgcn_mfma_f32_16x16x32_bf16(A0.v, B.v, acc0, 0, 0, 0);
        acc1 = __builtin_amdgcn_mfma_f32_16x16x32_bf16(A1.v, B.v, acc1, 0, 0, 0);
    }

    // C/D layout: col = lane&15, row(t) = quad*4 + reg.
    // Plain float2 stores into this chunk's slab (each addr written once;
    // padding lanes duplicate node 0 with identical values — benign).
    float* slab = fws + (size_t)chunk * SLAB;
    #pragma unroll
    for (int r = 0; r < 4; ++r) {
        int t = quad * 4 + r;
        *(float2*)&slab[((size_t)n * T_DIM + t) * 2] = make_float2(acc0[r], acc1[r]);
    }
}

// ---------------------------------------------------------------------------
// Gather f_in = f[node_in-1] (256000 fp32) + boundary sums f_b (96 fp32).
// f = sum of the 8 chunk slabs (only referenced nodes are ever read).
// ---------------------------------------------------------------------------
__global__ __launch_bounds__(256) void gather_kernel(
    const float* __restrict__ fws,
    const int* __restrict__ node_in,
    const int* __restrict__ top, const int* __restrict__ bottom,
    const int* __restrict__ left, const int* __restrict__ right,
    float* __restrict__ out)
{
    const int tid = threadIdx.x;
    if (blockIdx.x < 1000) {
        int e = blockIdx.x * 256 + tid;        // < 256000
        int j = e >> 5;                        // node_in index
        int rem = e & 31;                      // t*2 + o
        size_t base = (size_t)(node_in[j] - 1) * 32 + rem;
        float v = 0.f;
        #pragma unroll
        for (int c = 0; c < CHUNKS; ++c) v += fws[c * (size_t)SLAB + base];
        out[e] = v;
    } else {
        __shared__ float red[256];
        __shared__ float sums[64];
        const int l = tid >> 6;                // 0=top 1=bottom 2=left 3=right
        const int t = (tid >> 2) & 15;
        const int p = tid & 3;
        const int* lists[4] = {top, bottom, left, right};
        const int osel = (l < 2) ? 1 : 0;
        const int* lp = lists[l];
        float s = 0.f;
        for (int idx = p; idx < NB; idx += 4) {
            size_t base = (size_t)(lp[idx] - 1) * 32 + t * 2 + osel;
            #pragma unroll
            for (int c = 0; c < CHUNKS; ++c) s += fws[c * (size_t)SLAB + base];
        }
        red[tid] = s;
        __syncthreads();
        if (p == 0)
            sums[tid >> 2] = red[tid] + red[tid + 1] + red[tid + 2] + red[tid + 3];
        __syncthreads();
        if (tid < 96) {
            int row = tid >> 4;                // 0..5 -> [top,bot,left,right,t+b,l+r]
            int tt = tid & 15;
            float v;
            if (row < 4)       v = sums[row * 16 + tt];
            else if (row == 4) v = sums[0 * 16 + tt] + sums[1 * 16 + tt];
            else               v = sums[2 * 16 + tt] + sums[3 * 16 + tt];
            out[256000 + tid] = v;
        }
    }
}

extern "C" void kernel_launch(void* const* d_in, const int* in_sizes, int n_in,
                              void* d_out, int out_size, void* d_ws, size_t ws_size,
                              hipStream_t stream)
{
    const float* x      = (const float*)d_in[0];
    const float* weight = (const float*)d_in[1];
    const int* node_in = (const int*)d_in[2];
    const int* top     = (const int*)d_in[3];
    const int* bottom  = (const int*)d_in[4];
    const int* left    = (const int*)d_in[5];
    const int* right   = (const int*)d_in[6];

    float* fws   = (float*)d_ws;                       // 8 slabs x 1.28 MB
    int*   flags = (int*)(fws + (size_t)CHUNKS * SLAB); // 10000 ints
    int*   cnt   = flags + N_NODES;                    // 1 int
    int*   list  = cnt + 1;                            // up to 10000 ids
    float* out   = (float*)d_out;                      // 256000 f_in + 96 f_b

    flag_kernel<<<(N_IN + 4*NB + 255) / 256, 256, 0, stream>>>(
        node_in, top, bottom, left, right, flags, cnt);
    compact_kernel<<<(N_NODES + 255) / 256, 256, 0, stream>>>(flags, cnt, list);

    dim3 grid((TILES + 3) / 4, CHUNKS);                // 157 x 8 (worst case)
    gemm_kernel<<<grid, 256, 0, stream>>>(x, weight, list, cnt, fws);
    gather_kernel<<<1001, 256, 0, stream>>>(fws, node_in, top, bottom, left, right, out);
}

// Round 5
// 465.934 us; speedup vs baseline: 1.0855x; 1.0017x over previous
//
#include <hip/hip_runtime.h>
#include <stdint.h>

// Problem constants (from reference) — all inputs/outputs are FP32.
#define T_DIM 16
#define M_DIM 1024
#define N_NODES 10000
#define NB 100
#define N_IN 8000
#define KI 4096             // i dimension (4*M)
#define KP 8192             // interleaved i' = 2*i + o (memory-contiguous axis of weight)
#define CHUNKS 8
#define I_CHUNK (KI / CHUNKS)        // 512 i-values per chunk
#define M_CHUNK (I_CHUNK / 4)        // 128 m-values per chunk
#define STEPS ((KP / CHUNKS) / 32)   // 32 MFMA k-steps per chunk
#define PITCH (I_CHUNK + 4)          // 516 shorts row pitch (8B aligned; 258 words %32=2 -> conflict-free)
#define TILES 625                    // worst-case tiles over all 10000 nodes
#define SLAB (N_NODES * T_DIM * 2)   // 320000 floats per chunk-slab

typedef short short8 __attribute__((ext_vector_type(8)));
typedef float f32x4 __attribute__((ext_vector_type(4)));

__device__ __forceinline__ unsigned int fbits(float f) {
    return __builtin_bit_cast(unsigned int, f);
}
// fp32 -> bf16 (RNE), result in low 16 bits
__device__ __forceinline__ unsigned int bf16rne(unsigned int u) {
    return (u + 0x7FFFu + ((u >> 16) & 1u)) >> 16;
}
__device__ __forceinline__ unsigned int pack2bf(float a, float b) {
    return bf16rne(fbits(a)) | (bf16rne(fbits(b)) << 16);
}

// ---------------------------------------------------------------------------
// Dedup: flag all referenced nodes in LDS, compact into a dense id list.
// Single block (1024 threads) — no global flags array, no extra dispatch.
// ---------------------------------------------------------------------------
__global__ __launch_bounds__(1024) void dedup_kernel(
    const int* __restrict__ node_in,
    const int* __restrict__ top, const int* __restrict__ bottom,
    const int* __restrict__ left, const int* __restrict__ right,
    int* __restrict__ counter, int* __restrict__ list)
{
    __shared__ int flags[N_NODES];       // 40 KB
    __shared__ int lcnt;
    const int tid = threadIdx.x;
    for (int i = tid; i < N_NODES; i += 1024) flags[i] = 0;
    if (tid == 0) lcnt = 0;
    __syncthreads();
    for (int i = tid; i < N_IN + 4 * NB; i += 1024) {
        int v;
        if (i < N_IN)              v = node_in[i];
        else if (i < N_IN + NB)    v = top[i - N_IN];
        else if (i < N_IN + 2*NB)  v = bottom[i - N_IN - NB];
        else if (i < N_IN + 3*NB)  v = left[i - N_IN - 2*NB];
        else                       v = right[i - N_IN - 3*NB];
        flags[v - 1] = 1;
    }
    __syncthreads();
    for (int i = tid; i < N_NODES; i += 1024) {
        if (flags[i]) {
            int pos = atomicAdd(&lcnt, 1);
            list[pos] = i;
        }
    }
    __syncthreads();
    if (tid == 0) *counter = lcnt;
}

// ---------------------------------------------------------------------------
// GEMM over REFERENCED nodes only: f[n,t,o] = sum_i x_out[t,i] * W[n,i,o]
// (fp32 in, fp32 acc, bf16 MFMA). K' = 8192 interleaved (i,o). B fragment =
// 8 consecutive fp32 weights/lane converted to bf16 in-register. A0/A1 =
// x_out with zeros at odd/even k' slots -> o=0 / o=1 accumulators (two MFMAs
// share one weight load). Each wave owns one (16-node tile from `list`,
// K-chunk) pair; partials go to per-chunk slabs with plain stores.
// grid = (157 tile-groups, 8 K-chunks) x 256 threads (4 waves, 1 tile each);
// waves past the compacted count exit right after the staging barrier.
// ---------------------------------------------------------------------------
__global__ __launch_bounds__(256) void gemm_kernel(
    const float* __restrict__ x,       // fp32 [16][3][1024]
    const float* __restrict__ weight,  // fp32 [10000][4096][2]
    const int* __restrict__ list,      // compacted referenced node ids
    const int* __restrict__ counter,   // number of referenced nodes
    float* __restrict__ fws)           // fp32 [8][10000][16][2] partial slabs
{
    __shared__ unsigned short lds_x[T_DIM * PITCH];   // x_out chunk as bf16

    const int tid = threadIdx.x;
    const int chunk = blockIdx.y;

    // Stage this chunk's x_out[t, i] into LDS as bf16.
    // x_out[t, 4m + {0,1,2,3}] = [x[t,0,m], x[t,2,m], x[t,2,m], x[t,1,m]]
    for (int q = tid; q < T_DIM * M_CHUNK; q += 256) {
        int t = q >> 7;            // M_CHUNK == 128 per t
        int mloc = q & 127;
        int m = chunk * M_CHUNK + mloc;
        const float* xb = x + t * 3 * M_DIM + m;
        float v0 = xb[0];
        float v1 = xb[M_DIM];
        float v2 = xb[2 * M_DIM];
        unsigned int w0 = pack2bf(v0, v2);   // slots 4m+0, 4m+1
        unsigned int w1 = pack2bf(v2, v1);   // slots 4m+2, 4m+3
        *(uint2*)&lds_x[t * PITCH + mloc * 4] = make_uint2(w0, w1);
    }
    __syncthreads();

    const int cnt = *counter;                 // wave-uniform scalar
    const int wave = tid >> 6;
    const int lane = tid & 63;
    const int tile = blockIdx.x * 4 + wave;
    if (tile * 16 >= cnt) return;             // whole wave unneeded

    const int col = lane & 15;   // n-slot within tile (B/C col)
    const int quad = lane >> 4;  // k-group
    const int idx = tile * 16 + col;
    const int n = (idx < cnt) ? list[idx] : 0;

    // B source: lane holds W'[k' = quad*8 + j][n], j contiguous in memory (fp32).
    const float* wp =
        weight + (size_t)n * KP + (size_t)chunk * (KP / CHUNKS) + quad * 8;
    // A source: 4 consecutive bf16 x_out values for t = lane&15.
    const unsigned short* xrow = &lds_x[(lane & 15) * PITCH + quad * 4];

    f32x4 acc0 = {0.f, 0.f, 0.f, 0.f};
    f32x4 acc1 = {0.f, 0.f, 0.f, 0.f};

    float4 flo = *(const float4*)wp;
    float4 fhi = *(const float4*)(wp + 4);
    #pragma unroll 4
    for (int s = 0; s < STEPS; ++s) {
        float4 lo = flo, hi = fhi;
        if (s + 1 < STEPS) {
            flo = *(const float4*)(wp + (s + 1) * 32);
            fhi = *(const float4*)(wp + (s + 1) * 32 + 4);
        }

        // Pack 8 fp32 weights -> 8 bf16 B fragment (k'-order = memory order).
        union { unsigned int ui[4]; short8 v; } B;
        B.ui[0] = pack2bf(lo.x, lo.y);
        B.ui[1] = pack2bf(lo.z, lo.w);
        B.ui[2] = pack2bf(hi.x, hi.y);
        B.ui[3] = pack2bf(hi.z, hi.w);

        uint2 u = *(const uint2*)(xrow + s * 16);
        union { unsigned int ui[4]; short8 v; } A0, A1;
        // A0: x values at even k'-slots (o=0 weights), A1: odd k'-slots (o=1).
        A0.ui[0] = u.x & 0xFFFFu;      A0.ui[1] = u.x >> 16;
        A0.ui[2] = u.y & 0xFFFFu;      A0.ui[3] = u.y >> 16;
        A1.ui[0] = u.x << 16;          A1.ui[1] = u.x & 0xFFFF0000u;
        A1.ui[2] = u.y << 16;          A1.ui[3] = u.y & 0xFFFF0000u;

        acc0 = __builtin_amdgcn_mfma_f32_16x16x32_bf16(A0.v, B.v, acc0, 0, 0, 0);
        acc1 = __builtin_amdgcn_mfma_f32_16x16x32_bf16(A1.v, B.v, acc1, 0, 0, 0);
    }

    // C/D layout: col = lane&15, row(t) = quad*4 + reg.
    // Plain float2 stores into this chunk's slab (each addr written once;
    // padding lanes duplicate node 0 with identical values — benign).
    float* slab = fws + (size_t)chunk * SLAB;
    #pragma unroll
    for (int r = 0; r < 4; ++r) {
        int t = quad * 4 + r;
        *(float2*)&slab[((size_t)n * T_DIM + t) * 2] = make_float2(acc0[r], acc1[r]);
    }
}

// ---------------------------------------------------------------------------
// Gather f_in = f[node_in-1] (256000 fp32, float4-vectorized: 8 threads/node)
// + boundary sums f_b (96 fp32). f = sum of the 8 chunk slabs (LLC-resident).
// ---------------------------------------------------------------------------
__global__ __launch_bounds__(256) void gather_kernel(
    const float* __restrict__ fws,
    const int* __restrict__ node_in,
    const int* __restrict__ top, const int* __restrict__ bottom,
    const int* __restrict__ left, const int* __restrict__ right,
    float* __restrict__ out)
{
    const int tid = threadIdx.x;
    if (blockIdx.x < 250) {
        int e4 = blockIdx.x * 1024 + tid * 4;  // element base; 256000 = 250*1024
        int j = e4 >> 5;                       // node_in index (32 elems/node)
        int rem = e4 & 31;                     // (t*2+o) base, 16B aligned
        size_t base = (size_t)(node_in[j] - 1) * 32 + rem;
        float4 v = {0.f, 0.f, 0.f, 0.f};
        #pragma unroll
        for (int c = 0; c < CHUNKS; ++c) {
            float4 s = *(const float4*)&fws[c * (size_t)SLAB + base];
            v.x += s.x; v.y += s.y; v.z += s.z; v.w += s.w;
        }
        *(float4*)&out[e4] = v;
    } else {
        __shared__ float red[256];
        __shared__ float sums[64];
        const int l = tid >> 6;                // 0=top 1=bottom 2=left 3=right
        const int t = (tid >> 2) & 15;
        const int p = tid & 3;
        const int* lists[4] = {top, bottom, left, right};
        const int osel = (l < 2) ? 1 : 0;
        const int* lp = lists[l];
        float s = 0.f;
        for (int idx = p; idx < NB; idx += 4) {
            size_t base = (size_t)(lp[idx] - 1) * 32 + t * 2 + osel;
            #pragma unroll
            for (int c = 0; c < CHUNKS; ++c) s += fws[c * (size_t)SLAB + base];
        }
        red[tid] = s;
        __syncthreads();
        if (p == 0)
            sums[tid >> 2] = red[tid] + red[tid + 1] + red[tid + 2] + red[tid + 3];
        __syncthreads();
        if (tid < 96) {
            int row = tid >> 4;                // 0..5 -> [top,bot,left,right,t+b,l+r]
            int tt = tid & 15;
            float v;
            if (row < 4)       v = sums[row * 16 + tt];
            else if (row == 4) v = sums[0 * 16 + tt] + sums[1 * 16 + tt];
            else               v = sums[2 * 16 + tt] + sums[3 * 16 + tt];
            out[256000 + tid] = v;
        }
    }
}

extern "C" void kernel_launch(void* const* d_in, const int* in_sizes, int n_in,
                              void* d_out, int out_size, void* d_ws, size_t ws_size,
                              hipStream_t stream)
{
    const float* x      = (const float*)d_in[0];
    const float* weight = (const float*)d_in[1];
    const int* node_in = (const int*)d_in[2];
    const int* top     = (const int*)d_in[3];
    const int* bottom  = (const int*)d_in[4];
    const int* left    = (const int*)d_in[5];
    const int* right   = (const int*)d_in[6];

    float* fws  = (float*)d_ws;                        // 8 slabs x 1.28 MB
    int*   cnt  = (int*)(fws + (size_t)CHUNKS * SLAB); // 1 int
    int*   list = cnt + 1;                             // up to 10000 ids
    float* out  = (float*)d_out;                       // 256000 f_in + 96 f_b

    dedup_kernel<<<1, 1024, 0, stream>>>(node_in, top, bottom, left, right, cnt, list);

    dim3 grid((TILES + 3) / 4, CHUNKS);                // 157 x 8 (worst case)
    gemm_kernel<<<grid, 256, 0, stream>>>(x, weight, list, cnt, fws);
    gather_kernel<<<251, 256, 0, stream>>>(fws, node_in, top, bottom, left, right, out);
}